// Round 4
// baseline (2907.183 us; speedup 1.0000x reference)
//
#include <hip/hip_runtime.h>

typedef __attribute__((ext_vector_type(8))) short bf16x8;
typedef __attribute__((ext_vector_type(4))) float f32x4;
typedef unsigned short ushort_t;
typedef unsigned int uint32;
typedef unsigned long long u64;

#define DEVI __device__ __forceinline__

static constexpr int Bn = 128, Sn = 256, In = 512, Hn = 512;
static constexpr int G3 = 3 * Hn;                 // 1536
static constexpr int GBLK = 32;                   // scan blocks (each owns 16 h-cols)

// ws layout (bytes)
static constexpr size_t GI_OFF    = 0;                              // bf16 [B*S][1536]
static constexpr size_t GI_BYTES  = (size_t)Bn * Sn * G3 * 2;       // 100,663,296
static constexpr size_t WIH_OFF   = GI_OFF + GI_BYTES;              // bf16 [1536][512]
static constexpr size_t WIH_BYTES = (size_t)G3 * In * 2;            // 1,572,864
static constexpr size_t HBUF_OFF  = WIH_OFF + WIH_BYTES;            // bf16 [2][B][H] as u64
static constexpr size_t HBUF_BYTES= (size_t)2 * Bn * Hn * 2;        // 262,144
static constexpr size_t FLAG_OFF  = HBUF_OFF + HBUF_BYTES;          // 32 flags, 128B stride
static constexpr size_t FLAG_BYTES= 4096;

DEVI ushort_t f2bf(float f) {
  uint32 u = __builtin_bit_cast(uint32, f);
  u += 0x7FFFu + ((u >> 16) & 1u);
  return (ushort_t)(u >> 16);
}
DEVI float bf2f(ushort_t h) {
  uint32 u = ((uint32)h) << 16;
  return __builtin_bit_cast(float, u);
}
DEVI float sigmoid_f(float x) { return 1.0f / (1.0f + __expf(-x)); }
DEVI float tanh_f(float x)    { return 2.0f / (1.0f + __expf(-2.0f * x)) - 1.0f; }

// Flag barrier, fail-fast. Caller guarantees prior h-stores were issued before
// entry; the __syncthreads() here emits s_waitcnt vmcnt(0) so they are at the
// coherence point before the flag store issues. First timeout sets *s_abort ->
// all later barriers no-op, kernel terminates in ~20ms worst case instead of
// wedging the container.
DEVI void gbar2(uint32* flags, int bid, int tid, uint32 want, int* s_abort) {
  __syncthreads();                     // drains vmcnt: h stores visible at L3
  if (*s_abort == 0) {
    if (tid == 0)
      __hip_atomic_store(flags + bid * 32, want, __ATOMIC_RELAXED,
                         __HIP_MEMORY_SCOPE_AGENT);
    if (tid < 32) {
      int ok = 0;
      for (int spin = 0; spin < 50000; ++spin) {   // ~20ms watchdog
        if (__hip_atomic_load(flags + tid * 32, __ATOMIC_RELAXED,
                              __HIP_MEMORY_SCOPE_AGENT) >= want) { ok = 1; break; }
        __builtin_amdgcn_s_sleep(1);
      }
      if (!ok) *s_abort = 1;           // 32 lanes racing same value: benign
    }
  }
  __syncthreads();
}

// --- kernel 0: convert W_ih f32 -> bf16 ---------------------------------
__global__ void k_cvt_wih(const float* __restrict__ wih, ushort_t* __restrict__ out) {
  int i = blockIdx.x * blockDim.x + threadIdx.x;   // float4 index, exact cover
  const float4 v = ((const float4*)wih)[i];
  ushort4 o;
  o.x = f2bf(v.x); o.y = f2bf(v.y); o.z = f2bf(v.z); o.w = f2bf(v.w);
  ((ushort4*)out)[i] = o;
}

// --- kernel 1: gi = x @ W_ih^T + b_ih  (bf16 out) -----------------------
__launch_bounds__(512)
__global__ void k_gi(const float* __restrict__ x, const ushort_t* __restrict__ wihb,
                     const float* __restrict__ b_ih, ushort_t* __restrict__ gi) {
  extern __shared__ ushort_t apan[];   // [128][520] bf16
  const int tid = threadIdx.x;
  const int bm  = blockIdx.x;          // rows [bm*128, +128)
#pragma unroll
  for (int it = 0; it < 32; ++it) {
    int fidx = it * 512 + tid;               // float4 index in [128][128]
    int row = fidx >> 7, c4 = fidx & 127;
    const float4 v = *(const float4*)(x + ((size_t)(bm * 128 + row) << 9) + (c4 << 2));
    ushort4 o;
    o.x = f2bf(v.x); o.y = f2bf(v.y); o.z = f2bf(v.z); o.w = f2bf(v.w);
    *(ushort4*)(&apan[row * 520 + (c4 << 2)]) = o;
  }
  __syncthreads();
  const int lane = tid & 63, wid = tid >> 6;
  const int l15 = lane & 15, hi = lane >> 4;
  const int arow = wid * 16 + l15;
  for (int nt = 0; nt < 12; ++nt) {
    const int n0 = nt * 128;
    f32x4 acc[8] = {};
#pragma unroll
    for (int ks = 0; ks < 16; ++ks) {
      bf16x8 a = *(const bf16x8*)(&apan[arow * 520 + ks * 32 + hi * 8]);
#pragma unroll
      for (int j = 0; j < 8; ++j) {
        const ushort_t* wp = wihb + ((size_t)(n0 + j * 16 + l15) << 9) + ks * 32 + hi * 8;
        bf16x8 b = *(const bf16x8*)wp;
        acc[j] = __builtin_amdgcn_mfma_f32_16x16x32_bf16(a, b, acc[j], 0, 0, 0);
      }
    }
#pragma unroll
    for (int j = 0; j < 8; ++j) {
      const int n = n0 + j * 16 + l15;
      const float bias = b_ih[n];
#pragma unroll
      for (int r = 0; r < 4; ++r) {
        int m = bm * 128 + wid * 16 + hi * 4 + r;   // D row = 4*(lane>>4)+reg
        gi[(size_t)m * 1536 + n] = f2bf(acc[j][r] + bias);
      }
    }
  }
}

// --- kernel 2: persistent masked-GRU scan -------------------------------
// 32 blocks x 512 threads, block b owns h-cols [16b,16b+16).
// Cross-block h exchange via relaxed AGENT-scope atomics (per-instruction
// cache-bypass to the coherence point). NO __threadfence: L2 never bulk
// flushed/invalidated, gi/mask/out stay cached. Barrier = per-block monotone
// flag on its own 128B line (plain store, no RMW) + 32-lane parallel poll.
__launch_bounds__(512)
__global__ void k_scan(const float* __restrict__ hx, const float* __restrict__ mask,
                       const float* __restrict__ whh, const float* __restrict__ bhh,
                       const ushort_t* __restrict__ gi, u64* __restrict__ hbuf,
                       uint32* __restrict__ flags, float* __restrict__ out) {
  __shared__ ushort_t Wl[48 * 520];     // 49,920 B
  __shared__ ushort_t hpack[128 * 16];  //  4,096 B (bf16 own-slice staging)
  __shared__ int s_abort;
  const int tid = threadIdx.x;
  const int bid = blockIdx.x;
  const int c0 = bid * 16;
  if (tid == 0) s_abort = 0;

  // stage W_hh slice (rows g*512 + c0 + j) as bf16
  for (int r = 0; r < 48; ++r) {
    int g = r >> 4, j = r & 15;
    Wl[r * 520 + tid] = f2bf(whh[(size_t)(g * 512 + c0 + j) * 512 + tid]);
  }

  const int lane = tid & 63, wid = tid >> 6;
  const int l15 = lane & 15, hi = lane >> 4;
  const int arow = wid * 16 + l15;

  // init own h slice in REGISTERS (f32) + publish bf16 h0 into hbuf[0]
  float hreg[4];
#pragma unroll
  for (int r = 0; r < 4; ++r) {
    int b = wid * 16 + hi * 4 + r;
    hreg[r] = hx[b * 512 + c0 + l15] * mask[b * 256];
    hpack[b * 16 + l15] = f2bf(hreg[r]);
  }
  __syncthreads();
  {
    int b = tid >> 2, q = tid & 3;     // one aligned 8B store per thread
    u64 v = *(const u64*)(&hpack[b * 16 + q * 4]);
    __hip_atomic_store(hbuf + (size_t)b * 128 + (c0 >> 2) + q, v,
                       __ATOMIC_RELAXED, __HIP_MEMORY_SCOPE_AGENT);
  }
  gbar2(flags, bid, tid, 1u, &s_abort);

  const float bhh_r = bhh[c0 + l15];
  const float bhh_z = bhh[512 + c0 + l15];
  const float bhh_n = bhh[1024 + c0 + l15];
  int p = 0;

  for (int t = 0; t < 256; ++t) {
    // gi + next-mask prefetch (plain cached loads, independent of h)
    float giv0[4], giv1[4], giv2[4], mk[4];
#pragma unroll
    for (int r = 0; r < 4; ++r) {
      int b = wid * 16 + hi * 4 + r;
      size_t gb = (size_t)(b * 256 + t) * 1536 + c0 + l15;
      giv0[r] = bf2f(gi[gb]);
      giv1[r] = bf2f(gi[gb + 512]);
      giv2[r] = bf2f(gi[gb + 1024]);
      mk[r] = (t < 255) ? mask[b * 256 + t + 1] : 0.0f;
    }

    // h fragment loads: issue all 32x8B agent-scope loads, then MFMA
    const u64* hb = hbuf + (size_t)p * (128 * 128);
    u64 a0[16], a1[16];
#pragma unroll
    for (int ks = 0; ks < 16; ++ks) {
      size_t base = (size_t)arow * 128 + ks * 8 + hi * 2;
      a0[ks] = __hip_atomic_load(hb + base, __ATOMIC_RELAXED, __HIP_MEMORY_SCOPE_AGENT);
      a1[ks] = __hip_atomic_load(hb + base + 1, __ATOMIC_RELAXED, __HIP_MEMORY_SCOPE_AGENT);
    }

    f32x4 acc[3] = {};
#pragma unroll
    for (int ks = 0; ks < 16; ++ks) {
      union { u64 q[2]; bf16x8 v; } ua;
      ua.q[0] = a0[ks]; ua.q[1] = a1[ks];
#pragma unroll
      for (int g = 0; g < 3; ++g) {
        bf16x8 w = *(const bf16x8*)(&Wl[(g * 16 + l15) * 520 + ks * 32 + hi * 8]);
        acc[g] = __builtin_amdgcn_mfma_f32_16x16x32_bf16(ua.v, w, acc[g], 0, 0, 0);
      }
    }

#pragma unroll
    for (int r = 0; r < 4; ++r) {
      int b = wid * 16 + hi * 4 + r;
      float rg = sigmoid_f(giv0[r] + acc[0][r] + bhh_r);
      float zg = sigmoid_f(giv1[r] + acc[1][r] + bhh_z);
      float ng = tanh_f(giv2[r] + rg * (acc[2][r] + bhh_n));
      float hn = (1.0f - zg) * ng + zg * hreg[r];
      out[(size_t)(b * 256 + t) * 512 + c0 + l15] = hn;           // hs[b][t][:]
      if (t == 255) {
        out[(size_t)(128 * 256) * 512 + b * 512 + c0 + l15] = hn; // h_last
      } else {
        float hm = hn * mk[r];
        hreg[r] = hm;
        hpack[b * 16 + l15] = f2bf(hm);
      }
    }

    if (t < 255) {
      __syncthreads();                 // hpack complete
      {
        int b = tid >> 2, q = tid & 3;
        u64 v = *(const u64*)(&hpack[b * 16 + q * 4]);
        __hip_atomic_store(hbuf + (size_t)(p ^ 1) * (128 * 128) + (size_t)b * 128 + (c0 >> 2) + q,
                           v, __ATOMIC_RELAXED, __HIP_MEMORY_SCOPE_AGENT);
      }
      gbar2(flags, bid, tid, (uint32)(t + 2), &s_abort);
      p ^= 1;
    }
  }
}

extern "C" void kernel_launch(void* const* d_in, const int* in_sizes, int n_in,
                              void* d_out, int out_size, void* d_ws, size_t ws_size,
                              hipStream_t stream) {
  (void)in_sizes; (void)n_in; (void)out_size; (void)ws_size;
  const float* x    = (const float*)d_in[0];
  const float* hx   = (const float*)d_in[1];
  const float* mask = (const float*)d_in[2];
  const float* Wih  = (const float*)d_in[3];
  const float* Whh  = (const float*)d_in[4];
  const float* bih  = (const float*)d_in[5];
  const float* bhh  = (const float*)d_in[6];
  float* out = (float*)d_out;
  char* ws = (char*)d_ws;
  ushort_t* gi    = (ushort_t*)(ws + GI_OFF);
  ushort_t* wihb  = (ushort_t*)(ws + WIH_OFF);
  u64*      hbuf  = (u64*)(ws + HBUF_OFF);
  uint32*   flags = (uint32*)(ws + FLAG_OFF);

  hipMemsetAsync(flags, 0, FLAG_BYTES, stream);             // reset barrier each call
  k_cvt_wih<<<768, 256, 0, stream>>>(Wih, wihb);            // 786,432 f32 -> bf16
  k_gi<<<256, 512, 128 * 520 * 2, stream>>>(x, wihb, bih, gi);
  k_scan<<<GBLK, 512, 0, stream>>>(hx, mask, Whh, bhh, gi, hbuf, flags, out);
}

// Round 5
// 2771.310 us; speedup vs baseline: 1.0490x; 1.0490x over previous
//
#include <hip/hip_runtime.h>

typedef __attribute__((ext_vector_type(8))) short bf16x8;
typedef __attribute__((ext_vector_type(4))) float f32x4;
typedef unsigned short ushort_t;
typedef unsigned int uint32;
typedef unsigned long long u64;

#define DEVI __device__ __forceinline__

static constexpr int Bn = 128, Sn = 256, In = 512, Hn = 512;
static constexpr int G3 = 3 * Hn;                 // 1536
static constexpr int GBLK = 32;                   // scan blocks (each owns 16 h-cols)

// ws layout (bytes)
static constexpr size_t GI_OFF    = 0;                              // bf16 [B*S][1536]
static constexpr size_t GI_BYTES  = (size_t)Bn * Sn * G3 * 2;       // 100,663,296
static constexpr size_t WIH_OFF   = GI_OFF + GI_BYTES;              // bf16 [1536][512]
static constexpr size_t WIH_BYTES = (size_t)G3 * In * 2;            // 1,572,864
static constexpr size_t HBUF_OFF  = WIH_OFF + WIH_BYTES;            // bf16 [2][B][H] as u64
static constexpr size_t HBUF_BYTES= (size_t)2 * Bn * Hn * 2;        // 262,144
static constexpr size_t FLAG_OFF  = HBUF_OFF + HBUF_BYTES;          // 32 flags, 128B stride
static constexpr size_t FLAG_BYTES= 4096;

DEVI ushort_t f2bf(float f) {
  uint32 u = __builtin_bit_cast(uint32, f);
  u += 0x7FFFu + ((u >> 16) & 1u);
  return (ushort_t)(u >> 16);
}
DEVI float bf2f(ushort_t h) {
  uint32 u = ((uint32)h) << 16;
  return __builtin_bit_cast(float, u);
}
DEVI float sigmoid_f(float x) { return 1.0f / (1.0f + __expf(-x)); }
DEVI float tanh_f(float x)    { return 2.0f / (1.0f + __expf(-2.0f * x)) - 1.0f; }

// --- kernel 0: convert W_ih f32 -> bf16 ---------------------------------
__global__ void k_cvt_wih(const float* __restrict__ wih, ushort_t* __restrict__ out) {
  int i = blockIdx.x * blockDim.x + threadIdx.x;   // float4 index, exact cover
  const float4 v = ((const float4*)wih)[i];
  ushort4 o;
  o.x = f2bf(v.x); o.y = f2bf(v.y); o.z = f2bf(v.z); o.w = f2bf(v.w);
  ((ushort4*)out)[i] = o;
}

// --- kernel 1: gi = x @ W_ih^T + b_ih  (bf16 out) -----------------------
__launch_bounds__(512)
__global__ void k_gi(const float* __restrict__ x, const ushort_t* __restrict__ wihb,
                     const float* __restrict__ b_ih, ushort_t* __restrict__ gi) {
  extern __shared__ ushort_t apan[];   // [128][520] bf16
  const int tid = threadIdx.x;
  const int bm  = blockIdx.x;          // rows [bm*128, +128)
#pragma unroll
  for (int it = 0; it < 32; ++it) {
    int fidx = it * 512 + tid;               // float4 index in [128][128]
    int row = fidx >> 7, c4 = fidx & 127;
    const float4 v = *(const float4*)(x + ((size_t)(bm * 128 + row) << 9) + (c4 << 2));
    ushort4 o;
    o.x = f2bf(v.x); o.y = f2bf(v.y); o.z = f2bf(v.z); o.w = f2bf(v.w);
    *(ushort4*)(&apan[row * 520 + (c4 << 2)]) = o;
  }
  __syncthreads();
  const int lane = tid & 63, wid = tid >> 6;
  const int l15 = lane & 15, hi = lane >> 4;
  const int arow = wid * 16 + l15;
  for (int nt = 0; nt < 12; ++nt) {
    const int n0 = nt * 128;
    f32x4 acc[8] = {};
#pragma unroll
    for (int ks = 0; ks < 16; ++ks) {
      bf16x8 a = *(const bf16x8*)(&apan[arow * 520 + ks * 32 + hi * 8]);
#pragma unroll
      for (int j = 0; j < 8; ++j) {
        const ushort_t* wp = wihb + ((size_t)(n0 + j * 16 + l15) << 9) + ks * 32 + hi * 8;
        bf16x8 b = *(const bf16x8*)wp;
        acc[j] = __builtin_amdgcn_mfma_f32_16x16x32_bf16(a, b, acc[j], 0, 0, 0);
      }
    }
#pragma unroll
    for (int j = 0; j < 8; ++j) {
      const int n = n0 + j * 16 + l15;
      const float bias = b_ih[n];
#pragma unroll
      for (int r = 0; r < 4; ++r) {
        int m = bm * 128 + wid * 16 + hi * 4 + r;   // D row = 4*(lane>>4)+reg
        gi[(size_t)m * 1536 + n] = f2bf(acc[j][r] + bias);
      }
    }
  }
}

// --- kernel 2: persistent masked-GRU scan -------------------------------
// 32 blocks x 512 threads, block b owns h-cols [16b,16b+16).
// Round-5 changes vs round-4 (both target serialized latency, the measured
// 9.7us/step cost):
//  (1) all 32 agent-scope h-loads issued into a live register array, fenced
//      by sched_barrier(0) so the scheduler cannot sink them into the MFMA
//      loop -> one ~700cy L3 round trip instead of 16 serialized ones.
//  (2) gi/mask loads for step t+1 are issued (raw, unconverted) right after
//      the flag store, so their ~900cy HBM latency hides under the poll.
__launch_bounds__(512)
__global__ void k_scan(const float* __restrict__ hx, const float* __restrict__ mask,
                       const float* __restrict__ whh, const float* __restrict__ bhh,
                       const ushort_t* __restrict__ gi, u64* __restrict__ hbuf,
                       uint32* __restrict__ flags, float* __restrict__ out) {
  __shared__ ushort_t Wl[48 * 520];     // 49,920 B
  __shared__ ushort_t hpack[128 * 16];  //  4,096 B (bf16 own-slice staging)
  __shared__ int s_abort;
  const int tid = threadIdx.x;
  const int bid = blockIdx.x;
  const int c0 = bid * 16;
  if (tid == 0) s_abort = 0;

  // stage W_hh slice (rows g*512 + c0 + j) as bf16
  for (int r = 0; r < 48; ++r) {
    int g = r >> 4, j = r & 15;
    Wl[r * 520 + tid] = f2bf(whh[(size_t)(g * 512 + c0 + j) * 512 + tid]);
  }

  const int lane = tid & 63, wid = tid >> 6;
  const int l15 = lane & 15, hi = lane >> 4;
  const int arow = wid * 16 + l15;

  // init own h slice in REGISTERS (f32) + publish bf16 h0 into hbuf[0]
  float hreg[4];
#pragma unroll
  for (int r = 0; r < 4; ++r) {
    int b = wid * 16 + hi * 4 + r;
    hreg[r] = hx[b * 512 + c0 + l15] * mask[b * 256];
    hpack[b * 16 + l15] = f2bf(hreg[r]);
  }
  __syncthreads();
  {
    int b = tid >> 2, q = tid & 3;     // one aligned 8B store per thread
    u64 v = *(const u64*)(&hpack[b * 16 + q * 4]);
    __hip_atomic_store(hbuf + (size_t)b * 128 + (c0 >> 2) + q, v,
                       __ATOMIC_RELAXED, __HIP_MEMORY_SCOPE_AGENT);
  }

  // prefetch gi/mask for t=0 (raw bf16 bits; convert at use)
  ushort_t pg0[4], pg1[4], pg2[4];
  float pmk[4];
#pragma unroll
  for (int r = 0; r < 4; ++r) {
    int b = wid * 16 + hi * 4 + r;
    size_t gb = (size_t)(b * 256 + 0) * 1536 + c0 + l15;
    pg0[r] = gi[gb];
    pg1[r] = gi[gb + 512];
    pg2[r] = gi[gb + 1024];
    pmk[r] = mask[b * 256 + 1];
  }

  // initial barrier: publish h0, wait all
  __syncthreads();                     // drains vmcnt: h0 stores at L3
  if (s_abort == 0) {
    if (tid == 0)
      __hip_atomic_store(flags + bid * 32, 1u, __ATOMIC_RELAXED,
                         __HIP_MEMORY_SCOPE_AGENT);
    if (tid < 32) {
      int ok = 0;
      for (int spin = 0; spin < 50000; ++spin) {
        if (__hip_atomic_load(flags + tid * 32, __ATOMIC_RELAXED,
                              __HIP_MEMORY_SCOPE_AGENT) >= 1u) { ok = 1; break; }
        __builtin_amdgcn_s_sleep(1);
      }
      if (!ok) s_abort = 1;
    }
  }
  __syncthreads();

  const float bhh_r = bhh[c0 + l15];
  const float bhh_z = bhh[512 + c0 + l15];
  const float bhh_n = bhh[1024 + c0 + l15];
  int p = 0;

  for (int t = 0; t < 256; ++t) {
    // (1) issue ALL 32 h-fragment loads, keep them live, fence the scheduler
    const u64* hb = hbuf + (size_t)p * (128 * 128);
    u64 ha[32];
#pragma unroll
    for (int ks = 0; ks < 16; ++ks) {
      size_t base = (size_t)arow * 128 + ks * 8 + hi * 2;
      ha[2 * ks]     = __hip_atomic_load(hb + base, __ATOMIC_RELAXED, __HIP_MEMORY_SCOPE_AGENT);
      ha[2 * ks + 1] = __hip_atomic_load(hb + base + 1, __ATOMIC_RELAXED, __HIP_MEMORY_SCOPE_AGENT);
    }
    __builtin_amdgcn_sched_barrier(0);   // loads stay clustered above MFMAs

    f32x4 acc[3] = {};
#pragma unroll
    for (int ks = 0; ks < 16; ++ks) {
      union { u64 q[2]; bf16x8 v; } ua;
      ua.q[0] = ha[2 * ks]; ua.q[1] = ha[2 * ks + 1];
#pragma unroll
      for (int g = 0; g < 3; ++g) {
        bf16x8 w = *(const bf16x8*)(&Wl[(g * 16 + l15) * 520 + ks * 32 + hi * 8]);
        acc[g] = __builtin_amdgcn_mfma_f32_16x16x32_bf16(ua.v, w, acc[g], 0, 0, 0);
      }
    }

#pragma unroll
    for (int r = 0; r < 4; ++r) {
      int b = wid * 16 + hi * 4 + r;
      float rg = sigmoid_f(bf2f(pg0[r]) + acc[0][r] + bhh_r);
      float zg = sigmoid_f(bf2f(pg1[r]) + acc[1][r] + bhh_z);
      float ng = tanh_f(bf2f(pg2[r]) + rg * (acc[2][r] + bhh_n));
      float hn = (1.0f - zg) * ng + zg * hreg[r];
      out[(size_t)(b * 256 + t) * 512 + c0 + l15] = hn;           // hs[b][t][:]
      if (t == 255) {
        out[(size_t)(128 * 256) * 512 + b * 512 + c0 + l15] = hn; // h_last
      } else {
        float hm = hn * pmk[r];
        hreg[r] = hm;
        hpack[b * 16 + l15] = f2bf(hm);
      }
    }

    if (t < 255) {
      __syncthreads();                 // hpack complete
      {
        int b = tid >> 2, q = tid & 3;
        u64 v = *(const u64*)(&hpack[b * 16 + q * 4]);
        __hip_atomic_store(hbuf + (size_t)(p ^ 1) * (128 * 128) + (size_t)b * 128 + (c0 >> 2) + q,
                           v, __ATOMIC_RELAXED, __HIP_MEMORY_SCOPE_AGENT);
      }
      __syncthreads();                 // drains vmcnt: h(t+1) stores at L3
      if (s_abort == 0) {
        if (tid == 0)
          __hip_atomic_store(flags + bid * 32, (uint32)(t + 2), __ATOMIC_RELAXED,
                             __HIP_MEMORY_SCOPE_AGENT);
      }
      // (2) prefetch gi/mask for t+1 NOW — latency hides under the poll
      {
        int tn = t + 1;
#pragma unroll
        for (int r = 0; r < 4; ++r) {
          int b = wid * 16 + hi * 4 + r;
          size_t gb = (size_t)(b * 256 + tn) * 1536 + c0 + l15;
          pg0[r] = gi[gb];
          pg1[r] = gi[gb + 512];
          pg2[r] = gi[gb + 1024];
          pmk[r] = (tn < 255) ? mask[b * 256 + tn + 1] : 0.0f;
        }
      }
      if (s_abort == 0) {
        if (tid < 32) {
          uint32 want = (uint32)(t + 2);
          int ok = 0;
          for (int spin = 0; spin < 50000; ++spin) {
            if (__hip_atomic_load(flags + tid * 32, __ATOMIC_RELAXED,
                                  __HIP_MEMORY_SCOPE_AGENT) >= want) { ok = 1; break; }
            __builtin_amdgcn_s_sleep(1);
          }
          if (!ok) s_abort = 1;
        }
      }
      __syncthreads();
      p ^= 1;
    }
  }
}

extern "C" void kernel_launch(void* const* d_in, const int* in_sizes, int n_in,
                              void* d_out, int out_size, void* d_ws, size_t ws_size,
                              hipStream_t stream) {
  (void)in_sizes; (void)n_in; (void)out_size; (void)ws_size;
  const float* x    = (const float*)d_in[0];
  const float* hx   = (const float*)d_in[1];
  const float* mask = (const float*)d_in[2];
  const float* Wih  = (const float*)d_in[3];
  const float* Whh  = (const float*)d_in[4];
  const float* bih  = (const float*)d_in[5];
  const float* bhh  = (const float*)d_in[6];
  float* out = (float*)d_out;
  char* ws = (char*)d_ws;
  ushort_t* gi    = (ushort_t*)(ws + GI_OFF);
  ushort_t* wihb  = (ushort_t*)(ws + WIH_OFF);
  u64*      hbuf  = (u64*)(ws + HBUF_OFF);
  uint32*   flags = (uint32*)(ws + FLAG_OFF);

  hipMemsetAsync(flags, 0, FLAG_BYTES, stream);             // reset barrier each call
  k_cvt_wih<<<768, 256, 0, stream>>>(Wih, wihb);            // 786,432 f32 -> bf16
  k_gi<<<256, 512, 128 * 520 * 2, stream>>>(x, wihb, bih, gi);
  k_scan<<<GBLK, 512, 0, stream>>>(hx, mask, Whh, bhh, gi, hbuf, flags, out);
}